// Round 1
// baseline (377.869 us; speedup 1.0000x reference)
//
#include <hip/hip_runtime.h>
#include <hip/hip_bf16.h>
#include <math.h>

// ConcatMLPAggregator R6: fused design.
//  prep:  pack W1/W2 to bf16 MFMA-B-fragment order; zero row. (unchanged)
//  fused: mask decode -> row pointers in LDS; GEMM1 A-fragments are loaded
//         DIRECTLY from v (8 consecutive floats of a gathered row == one
//         A-fragment), converted f32->bf16 in-register, fed to MFMA.
//         Eliminates the 64 MiB Xp intermediate (67 MB write + 67 MB read)
//         and one device-wide kernel boundary.

typedef __attribute__((ext_vector_type(8))) short bf16x8;
typedef __attribute__((ext_vector_type(4))) float f32x4;
typedef __attribute__((ext_vector_type(4))) unsigned int u32x4;

#define NCHAINS 32768
#define LPOS    64
#define DV      128
#define HID     128
#define KDIM    1024
#define CPB     32

__device__ __forceinline__ unsigned short cvt_bf16(float a) {
  unsigned u = __float_as_uint(a);
  u += 0x7fffu + ((u >> 16) & 1u);
  return (unsigned short)(u >> 16);
}
__device__ __forceinline__ unsigned pk2_bf16(float a, float b) {
  unsigned ua = __float_as_uint(a), ub = __float_as_uint(b);
  ua += 0x7fffu + ((ua >> 16) & 1u);
  ub += 0x7fffu + ((ub >> 16) & 1u);
  return (ua >> 16) | (ub & 0xffff0000u);
}
__device__ __forceinline__ float gelu_exact(float x) {
  return 0.5f * x * (1.0f + erff(x * 0.70710678118654752f));
}

// Wp[((ch*8 + nt)*64 + lane)*8 + j] = bf16(W[k][n]), k=ch*32+((lane>>4)&3)*8+j, n=nt*16+(lane&15)
__global__ __launch_bounds__(256) void prep_kernel(
    const float* __restrict__ W1, const float* __restrict__ W2,
    unsigned short* __restrict__ W1p, unsigned short* __restrict__ W2p,
    float* __restrict__ zr) {
  int id = blockIdx.x * 256 + threadIdx.x;   // 131072 total
  {
    int j = id & 7, lx = (id >> 3) & 63, nt = (id >> 9) & 7, ch = id >> 12;
    int k = ch * 32 + ((lx >> 4) & 3) * 8 + j;
    int n = nt * 16 + (lx & 15);
    W1p[id] = cvt_bf16(W1[k * HID + n]);
    if (id < 16384) {
      int ch2 = id >> 12;
      int k2 = ch2 * 32 + ((lx >> 4) & 3) * 8 + j;
      W2p[id] = cvt_bf16(W2[k2 * HID + n]);
    }
  }
  if (id < DV) zr[id] = 0.0f;
}

// Block = 32 chains (one gemm tile-pair). 1024 blocks x 256 threads.
__global__ __launch_bounds__(256, 4) void fused_kernel(
    const float* __restrict__ v, const int* __restrict__ batch_idx,
    const int* __restrict__ mask, const int* __restrict__ count,
    const float* __restrict__ W1, const float* __restrict__ b1,
    const float* __restrict__ b2,
    const unsigned short* __restrict__ W1p, const unsigned short* __restrict__ W2p,
    const float* __restrict__ zr, float* __restrict__ out) {
  __shared__ const float* s_rp[CPB][9];   // [chain-in-block][slot]; 9 pads banks
  __shared__ float s_logc[CPB];
  __shared__ unsigned short s_H[CPB][HID + 8];

  const int tid = threadIdx.x;
  const int blk = blockIdx.x;

  // ---- decode: first 8 set mask bits -> row pointers (zr for empty slots) ----
  if (tid < CPB) {
    int c = blk * CPB + tid;
    s_logc[tid] = log1pf((float)count[c]);
    const int4* mp = (const int4*)(mask + (size_t)c * LPOS);
    unsigned long long m64 = 0;
    #pragma unroll
    for (int q = 0; q < 16; q++) {
      int4 mm = mp[q];
      unsigned long long b = (mm.x != 0 ? 1ull : 0ull) | (mm.y != 0 ? 2ull : 0ull) |
                             (mm.z != 0 ? 4ull : 0ull) | (mm.w != 0 ? 8ull : 0ull);
      m64 |= b << (q * 4);
    }
    const float* base = v + (size_t)batch_idx[c] * (LPOS * DV);
    #pragma unroll
    for (int s = 0; s < 8; s++) {
      const float* p;
      if (m64) {
        int pos = __ffsll(m64) - 1;
        m64 &= (m64 - 1);
        p = base + pos * DV;
      } else {
        p = zr;
      }
      s_rp[tid][s] = p;
    }
  }
  __syncthreads();

  const int l = tid & 63, w = tid >> 6;
  const int mh = w & 1, cb = w >> 1;          // mh: chain half-tile, cb: n-half
  const int m = l & 15, kq = l >> 4;          // A-frag: row=m, k=kq*8+j (per K=32 chunk)
  const int mrow = mh * 16 + m;

  const unsigned short* bp = W1p + ((size_t)(cb * 4) * 64 + l) * 8;

  f32x4 acc0 = {0.f,0.f,0.f,0.f}, acc1 = {0.f,0.f,0.f,0.f};
  f32x4 acc2 = {0.f,0.f,0.f,0.f}, acc3 = {0.f,0.f,0.f,0.f};

  // ---- GEMM1: A-fragments straight from v (gather fused into the K-loop) ----
  // k = ch*32 + kq*8 + j, ch = s*4 + dc  =>  row p[s], float offset dc*32 + kq*8.
  #pragma unroll
  for (int s = 0; s < 8; s++) {               // MUST be fully unrolled (static s)
    const float* ps = s_rp[mrow][s] + kq * 8;
    #pragma unroll
    for (int dc = 0; dc < 4; dc++) {
      const int ch = s * 4 + dc;
      float4 x0 = *(const float4*)(ps + dc * 32);
      float4 x1 = *(const float4*)(ps + dc * 32 + 4);
      u32x4 ua;
      ua.x = pk2_bf16(x0.x, x0.y);
      ua.y = pk2_bf16(x0.z, x0.w);
      ua.z = pk2_bf16(x1.x, x1.y);
      ua.w = pk2_bf16(x1.z, x1.w);
      bf16x8 a = __builtin_bit_cast(bf16x8, ua);
      const unsigned short* wb = bp + (size_t)ch * 4096;
      bf16x8 b0  = *(const bf16x8*)(wb);
      bf16x8 b1f = *(const bf16x8*)(wb + 512);
      bf16x8 b2f = *(const bf16x8*)(wb + 1024);
      bf16x8 b3f = *(const bf16x8*)(wb + 1536);
      acc0 = __builtin_amdgcn_mfma_f32_16x16x32_bf16(a, b0,  acc0, 0, 0, 0);
      acc1 = __builtin_amdgcn_mfma_f32_16x16x32_bf16(a, b1f, acc1, 0, 0, 0);
      acc2 = __builtin_amdgcn_mfma_f32_16x16x32_bf16(a, b2f, acc2, 0, 0, 0);
      acc3 = __builtin_amdgcn_mfma_f32_16x16x32_bf16(a, b3f, acc3, 0, 0, 0);
    }
  }

  // ---- epilogue 1: + log_count*W1[last] + b1, GELU, -> s_H (bf16) ----
  {
    float w1l[4], b1v[4];
    #pragma unroll
    for (int nt = 0; nt < 4; nt++) {
      int n = cb * 64 + nt * 16 + m;
      w1l[nt] = W1[KDIM * HID + n];
      b1v[nt] = b1[n];
    }
    f32x4* accs[4] = {&acc0, &acc1, &acc2, &acc3};
    #pragma unroll
    for (int r = 0; r < 4; r++) {
      int row = mh * 16 + kq * 4 + r;   // C/D: row=(lane>>4)*4+reg, col=lane&15
      float lc = s_logc[row];
      #pragma unroll
      for (int nt = 0; nt < 4; nt++) {
        float h = (*accs[nt])[r] + lc * w1l[nt] + b1v[nt];
        s_H[row][cb * 64 + nt * 16 + m] = cvt_bf16(gelu_exact(h));
      }
    }
  }
  __syncthreads();

  // ---- GEMM2: H @ W2 ----
  f32x4 d0 = {0.f,0.f,0.f,0.f}, d1 = {0.f,0.f,0.f,0.f};
  f32x4 d2 = {0.f,0.f,0.f,0.f}, d3 = {0.f,0.f,0.f,0.f};

  #pragma unroll
  for (int ch = 0; ch < 4; ch++) {
    bf16x8 a = *(const bf16x8*)&s_H[mh * 16 + m][ch * 32 + kq * 8];
    const unsigned short* wb = W2p + ((size_t)(ch * 8 + cb * 4) * 64 + l) * 8;
    bf16x8 b0  = *(const bf16x8*)(wb);
    bf16x8 b1f = *(const bf16x8*)(wb + 512);
    bf16x8 b2f = *(const bf16x8*)(wb + 1024);
    bf16x8 b3f = *(const bf16x8*)(wb + 1536);
    d0 = __builtin_amdgcn_mfma_f32_16x16x32_bf16(a, b0,  d0, 0, 0, 0);
    d1 = __builtin_amdgcn_mfma_f32_16x16x32_bf16(a, b1f, d1, 0, 0, 0);
    d2 = __builtin_amdgcn_mfma_f32_16x16x32_bf16(a, b2f, d2, 0, 0, 0);
    d3 = __builtin_amdgcn_mfma_f32_16x16x32_bf16(a, b3f, d3, 0, 0, 0);
  }

  {
    float b2v[4];
    #pragma unroll
    for (int nt = 0; nt < 4; nt++) b2v[nt] = b2[cb * 64 + nt * 16 + m];
    f32x4* ds[4] = {&d0, &d1, &d2, &d3};
    #pragma unroll
    for (int r = 0; r < 4; r++) {
      int row = mh * 16 + kq * 4 + r;
      size_t o = (size_t)(blk * CPB + row) * DV;
      #pragma unroll
      for (int nt = 0; nt < 4; nt++) {
        out[o + cb * 64 + nt * 16 + m] = (*ds[nt])[r] + b2v[nt];
      }
    }
  }
}

extern "C" void kernel_launch(void* const* d_in, const int* in_sizes, int n_in,
                              void* d_out, int out_size, void* d_ws, size_t ws_size,
                              hipStream_t stream) {
  const float* v          = (const float*)d_in[0];
  const int* batch_idx    = (const int*)d_in[1];
  const int* mk           = (const int*)d_in[2];
  const int* count        = (const int*)d_in[3];
  const float* W1         = (const float*)d_in[4];
  const float* b1         = (const float*)d_in[5];
  const float* W2         = (const float*)d_in[6];
  const float* b2         = (const float*)d_in[7];
  float* out              = (float*)d_out;

  char* ws = (char*)d_ws;
  unsigned short* W1p = (unsigned short*)ws;                       // 262144 B
  unsigned short* W2p = (unsigned short*)(ws + 262144);            // 32768 B
  float* zr           = (float*)(ws + 262144 + 32768);             // 512 B

  prep_kernel<<<512, 256, 0, stream>>>(W1, W2, W1p, W2p, zr);
  fused_kernel<<<NCHAINS / CPB, 256, 0, stream>>>(
      v, batch_idx, mk, count, W1, b1, b2, W1p, W2p, zr, out);
}